// Round 1
// baseline (406.340 us; speedup 1.0000x reference)
//
#include <hip/hip_runtime.h>
#include <math.h>
#include <stdint.h>

#define M_ROWS 8192
#define N_COLS 16384
#define K_DIM  256
#define CHUNK  2048
#define NCHUNK 4

typedef _Float16 half8  __attribute__((ext_vector_type(8)));
typedef _Float16 half4v __attribute__((ext_vector_type(4)));
typedef float    vf4    __attribute__((ext_vector_type(4)));

__device__ __forceinline__ void gload16(const void* g, void* lds) {
  // async global->LDS, 16B per lane; LDS dest = wave-uniform base + lane*16
  __builtin_amdgcn_global_load_lds(
      (__attribute__((address_space(1))) void*)(void*)g,
      (__attribute__((address_space(3))) void*)lds, 16, 0, 0);
}

// ---------------- prep: fp16 copies + exact f32 norms -----------------
__global__ __launch_bounds__(256) void prep_kernel(
    const float* __restrict__ x, const float* __restrict__ w,
    float* __restrict__ x2, float* __restrict__ w2,
    _Float16* __restrict__ xh, _Float16* __restrict__ wh) {
  int row  = blockIdx.x * 4 + (threadIdx.x >> 6);  // one wave per row
  int lane = threadIdx.x & 63;
  const float* src; _Float16* dst; float* nrm;
  if (row < M_ROWS) {
    src = x + (size_t)row * K_DIM; dst = xh + (size_t)row * K_DIM; nrm = x2 + row;
  } else {
    int r = row - M_ROWS;
    src = w + (size_t)r * K_DIM; dst = wh + (size_t)r * K_DIM; nrm = w2 + r;
  }
  float4 v = ((const float4*)src)[lane];           // 64 lanes x 4 = 256
  float s = v.x*v.x + v.y*v.y + v.z*v.z + v.w*v.w;
  #pragma unroll
  for (int off = 32; off > 0; off >>= 1) s += __shfl_down(s, off);
  if (lane == 0) *nrm = s;
  half4v h; h[0]=(_Float16)v.x; h[1]=(_Float16)v.y; h[2]=(_Float16)v.z; h[3]=(_Float16)v.w;
  ((half4v*)dst)[lane] = h;
}

// ------------- GEMM + logit epilogue (m97-structure, f16 MFMA) -------------
// WS=true : A/B are fp16 (from ws), norms from global arrays, global_load_lds staging
// WS=false: A/B are f32 inputs, inline convert via reg staging, per-block norms
template <bool WS>
__global__ __launch_bounds__(256, 2) void gemm_logit(
    const void* __restrict__ Aptr, const void* __restrict__ Bptr,
    const float* __restrict__ x2g, const float* __restrict__ w2g,
    float* __restrict__ out, int mbase) {
  __shared__ _Float16 As[128 * 64];
  __shared__ _Float16 Bs[128 * 64];
  __shared__ float x2s[128];
  __shared__ float w2s[128];

  // bijective XCD swizzle: each XCD owns 16 contiguous col-tiles (w slice ~1MB fp16, L2-resident)
  int id  = blockIdx.x;            // grid = 16 row-tiles * 128 col-tiles = 2048
  int xcd = id & 7;
  int rt  = (id >> 3) & 15;
  int c2  = id >> 7;               // [0,16)
  int brow = mbase + rt * 128;
  int bcol = (xcd * 16 + c2) * 128;

  int tid = threadIdx.x, lane = tid & 63, wid = tid >> 6;
  int wr = wid >> 1, wc = wid & 1;  // 2x2 waves, each 64x64 output

  vf4 acc[4][4] = {};

  if (!WS) {  // per-block exact norms from f32 inputs
    const float* xf = (const float*)Aptr;
    const float* wf = (const float*)Bptr;
    const float* src = (tid < 128) ? xf + (size_t)(brow + tid) * K_DIM
                                   : wf + (size_t)(bcol + tid - 128) * K_DIM;
    float s = 0.f;
    for (int i = 0; i < 64; ++i) {
      float4 v = ((const float4*)src)[i];
      s += v.x*v.x + v.y*v.y + v.z*v.z + v.w*v.w;
    }
    if (tid < 128) x2s[tid] = s; else w2s[tid - 128] = s;
  }

  for (int kk = 0; kk < K_DIM; kk += 64) {
    if (WS) {
      const _Float16* A  = (const _Float16*)Aptr;
      const _Float16* Bm = (const _Float16*)Bptr;
      #pragma unroll
      for (int i = 0; i < 4; ++i) {
        int seg = wid * 4 + i;                 // 1KB segment = 8 rows of [*][64] fp16
        int r   = seg * 8 + (lane >> 3);
        const _Float16* ga = A  + (size_t)(brow + r) * K_DIM + kk + (lane & 7) * 8;
        const _Float16* gb = Bm + (size_t)(bcol + r) * K_DIM + kk + (lane & 7) * 8;
        gload16(ga, (char*)As + seg * 1024);
        gload16(gb, (char*)Bs + seg * 1024);
      }
    } else {
      const float* xf = (const float*)Aptr;
      const float* wf = (const float*)Bptr;
      #pragma unroll
      for (int i = 0; i < 8; ++i) {
        int idx = i * 256 + tid;               // 2048 float4 per tile
        int r = idx >> 4, kq = idx & 15;
        float4 va = ((const float4*)(xf + (size_t)(brow + r) * K_DIM + kk))[kq];
        float4 vb = ((const float4*)(wf + (size_t)(bcol + r) * K_DIM + kk))[kq];
        half4v ha; ha[0]=(_Float16)va.x; ha[1]=(_Float16)va.y; ha[2]=(_Float16)va.z; ha[3]=(_Float16)va.w;
        half4v hb; hb[0]=(_Float16)vb.x; hb[1]=(_Float16)vb.y; hb[2]=(_Float16)vb.z; hb[3]=(_Float16)vb.w;
        *(half4v*)&As[r * 64 + kq * 4] = ha;
        *(half4v*)&Bs[r * 64 + kq * 4] = hb;
      }
    }
    __syncthreads();   // compiler drains vmcnt(0)/lgkmcnt(0) before s_barrier

    #pragma unroll
    for (int ks = 0; ks < 2; ++ks) {          // two K=32 MFMA steps per BK=64
      half8 af[4], bf[4];
      #pragma unroll
      for (int m = 0; m < 4; ++m)
        af[m] = *(const half8*)&As[(wr*64 + m*16 + (lane & 15)) * 64 + ks*32 + (lane >> 4) * 8];
      #pragma unroll
      for (int n = 0; n < 4; ++n)
        bf[n] = *(const half8*)&Bs[(wc*64 + n*16 + (lane & 15)) * 64 + ks*32 + (lane >> 4) * 8];
      #pragma unroll
      for (int m = 0; m < 4; ++m)
        #pragma unroll
        for (int n = 0; n < 4; ++n)
          acc[m][n] = __builtin_amdgcn_mfma_f32_16x16x32_f16(af[m], bf[n], acc[m][n], 0, 0, 0);
    }
    __syncthreads();
  }

  // epilogue: logit = -2*sqrt(max(x2 + w2 - 2*xw, 0))
  #pragma unroll
  for (int m = 0; m < 4; ++m) {
    int rl = wr * 64 + m * 16 + ((lane >> 4) << 2);   // C/D: row=(lane>>4)*4+j
    #pragma unroll
    for (int n = 0; n < 4; ++n) {
      int cl = wc * 64 + n * 16 + (lane & 15);        // C/D: col=lane&15
      int c  = bcol + cl;
      float w2v = WS ? w2g[c] : w2s[cl];
      #pragma unroll
      for (int j = 0; j < 4; ++j) {
        int r = brow + rl + j;
        float x2v = WS ? x2g[r] : x2s[rl - (brow - mbase) + j - (rt*128 - rt*128)]; // == x2s[rl+j-?] see below
        // NOTE: for !WS, local row index within tile:
        if (!WS) x2v = x2s[(rl + j) - 0 - (0)];  // rl is already tile-local
        float d2 = x2v + w2v - 2.0f * acc[m][n][j];
        d2 = fmaxf(d2, 0.0f);
        out[(size_t)r * N_COLS + c] = -2.0f * sqrtf(d2);
      }
    }
  }
}

// ---------------- softmax normalize: one block per row -----------------
__global__ __launch_bounds__(256) void softmax_norm(float* __restrict__ io, int mbase) {
  int row = mbase + blockIdx.x;
  float* p = io + (size_t)row * N_COLS;
  int tid = threadIdx.x;
  __shared__ float wsum[4];

  float4 v[16];
  float s = 0.f;
  #pragma unroll
  for (int i = 0; i < 16; ++i) {
    v[i] = ((const float4*)p)[i * 256 + tid];
    v[i].x = __expf(v[i].x); v[i].y = __expf(v[i].y);
    v[i].z = __expf(v[i].z); v[i].w = __expf(v[i].w);
    s += v[i].x + v[i].y + v[i].z + v[i].w;
  }
  #pragma unroll
  for (int off = 32; off > 0; off >>= 1) s += __shfl_down(s, off);
  if ((tid & 63) == 0) wsum[tid >> 6] = s;
  __syncthreads();
  float inv = 1.0f / (wsum[0] + wsum[1] + wsum[2] + wsum[3]);
  #pragma unroll
  for (int i = 0; i < 16; ++i) {
    float4 o = v[i];
    o.x *= inv; o.y *= inv; o.z *= inv; o.w *= inv;
    ((float4*)p)[i * 256 + tid] = o;
  }
}

extern "C" void kernel_launch(void* const* d_in, const int* in_sizes, int n_in,
                              void* d_out, int out_size, void* d_ws, size_t ws_size,
                              hipStream_t stream) {
  const float* x = (const float*)d_in[0];
  const float* w = (const float*)d_in[1];
  float* out = (float*)d_out;

  // ws layout: x2[8192] f32 | w2[16384] f32 | xh fp16 [8192*256] | wh fp16 [16384*256]
  const size_t need = (size_t)(M_ROWS + N_COLS) * 4 + (size_t)(M_ROWS + N_COLS) * K_DIM * 2;
  char* ws = (char*)d_ws;
  float* x2 = (float*)ws;
  float* w2 = x2 + M_ROWS;
  _Float16* xh = (_Float16*)(w2 + N_COLS);
  _Float16* wh = xh + (size_t)M_ROWS * K_DIM;
  const bool useWS = (ws_size >= need);

  if (useWS) {
    prep_kernel<<<(M_ROWS + N_COLS) / 4, 256, 0, stream>>>(x, w, x2, w2, xh, wh);
  }
  for (int c = 0; c < NCHUNK; ++c) {
    int mbase = c * CHUNK;
    if (useWS)
      gemm_logit<true><<<(CHUNK / 128) * (N_COLS / 128), 256, 0, stream>>>(
          xh, wh, x2, w2, out, mbase);
    else
      gemm_logit<false><<<(CHUNK / 128) * (N_COLS / 128), 256, 0, stream>>>(
          x, w, nullptr, nullptr, out, mbase);
    softmax_norm<<<CHUNK, 256, 0, stream>>>(out, mbase);
  }
}

// Round 2
// 333.834 us; speedup vs baseline: 1.2172x; 1.2172x over previous
//
#include <hip/hip_runtime.h>
#include <math.h>
#include <stdint.h>

#define M_ROWS 8192
#define N_COLS 16384
#define K_DIM  256
#define NTILE  (N_COLS / 128)   // 128 col tiles
#define CHUNK  2048             // fallback path only
#define NCHUNK 4

typedef _Float16 half8  __attribute__((ext_vector_type(8)));
typedef _Float16 half4v __attribute__((ext_vector_type(4)));
typedef float    vf4    __attribute__((ext_vector_type(4)));

__device__ __forceinline__ void gload16(const void* g, void* lds) {
  // async global->LDS, 16B per lane; LDS dest = wave-uniform base + lane*16
  __builtin_amdgcn_global_load_lds(
      (__attribute__((address_space(1))) void*)(void*)g,
      (__attribute__((address_space(3))) void*)lds, 16, 0, 0);
}

// ---------------- prep: fp16 copies + exact f32 norms -----------------
__global__ __launch_bounds__(256) void prep_kernel(
    const float* __restrict__ x, const float* __restrict__ w,
    float* __restrict__ x2, float* __restrict__ w2,
    _Float16* __restrict__ xh, _Float16* __restrict__ wh) {
  int row  = blockIdx.x * 4 + (threadIdx.x >> 6);  // one wave per row
  int lane = threadIdx.x & 63;
  const float* src; _Float16* dst; float* nrm;
  if (row < M_ROWS) {
    src = x + (size_t)row * K_DIM; dst = xh + (size_t)row * K_DIM; nrm = x2 + row;
  } else {
    int r = row - M_ROWS;
    src = w + (size_t)r * K_DIM; dst = wh + (size_t)r * K_DIM; nrm = w2 + r;
  }
  float4 v = ((const float4*)src)[lane];           // 64 lanes x 4 = 256
  float s = v.x*v.x + v.y*v.y + v.z*v.z + v.w*v.w;
  #pragma unroll
  for (int off = 32; off > 0; off >>= 1) s += __shfl_down(s, off);
  if (lane == 0) *nrm = s;
  half4v h; h[0]=(_Float16)v.x; h[1]=(_Float16)v.y; h[2]=(_Float16)v.z; h[3]=(_Float16)v.w;
  ((half4v*)dst)[lane] = h;
}

// -------- recompute GEMM, m97 structure. MODE 0: row-sum partials.
// -------- MODE 1: write normalized softmax to out. --------------------
template <int MODE>
__global__ __launch_bounds__(256, 2) void gemm_pass(
    const _Float16* __restrict__ A, const _Float16* __restrict__ Bm,
    const float* __restrict__ x2g, const float* __restrict__ w2g,
    const float* __restrict__ invg,
    float* __restrict__ partials,
    float* __restrict__ out) {
  __shared__ _Float16 As[128 * 64];
  __shared__ _Float16 Bs[128 * 64];
  __shared__ float x2s[128];
  __shared__ float w2s[128];
  __shared__ float invs[128];
  __shared__ float rowpart[2][128];

  // XCD partition: xcd = id&7 owns 16 contiguous col-tiles (w slice 1MB, L2-resident);
  // within an XCD, col-tile varies fastest -> A-tile reused 16x consecutively.
  int id   = blockIdx.x;            // grid = 64 row-tiles * 128 col-tiles = 8192
  int xcd  = id & 7;
  int rest = id >> 3;               // 0..1023
  int ct   = xcd * 16 + (rest & 15);
  int rt   = rest >> 4;             // 0..63
  int brow = rt * 128;
  int bcol = ct * 128;

  int tid = threadIdx.x, lane = tid & 63, wid = tid >> 6;
  int wr = wid >> 1, wc = wid & 1;  // 2x2 waves, each 64x64 output

  if (tid < 128) {
    x2s[tid] = x2g[brow + tid];
    if (MODE == 1) invs[tid] = invg[brow + tid];
  } else {
    w2s[tid - 128] = w2g[bcol + tid - 128];
  }

  vf4 acc[4][4] = {};

  for (int kk = 0; kk < K_DIM; kk += 64) {
    #pragma unroll
    for (int i = 0; i < 4; ++i) {
      int seg = wid * 4 + i;                 // 1KB segment = 8 rows of [*][64] fp16
      int r   = seg * 8 + (lane >> 3);
      gload16(A  + (size_t)(brow + r) * K_DIM + kk + (lane & 7) * 8, (char*)As + seg * 1024);
      gload16(Bm + (size_t)(bcol + r) * K_DIM + kk + (lane & 7) * 8, (char*)Bs + seg * 1024);
    }
    __syncthreads();   // compiler drains vmcnt(0) before s_barrier

    #pragma unroll
    for (int ks = 0; ks < 2; ++ks) {          // two K=32 MFMA steps per BK=64
      half8 af[4], bf[4];
      #pragma unroll
      for (int m = 0; m < 4; ++m)
        af[m] = *(const half8*)&As[(wr*64 + m*16 + (lane & 15)) * 64 + ks*32 + (lane >> 4) * 8];
      #pragma unroll
      for (int n = 0; n < 4; ++n)
        bf[n] = *(const half8*)&Bs[(wc*64 + n*16 + (lane & 15)) * 64 + ks*32 + (lane >> 4) * 8];
      #pragma unroll
      for (int m = 0; m < 4; ++m)
        #pragma unroll
        for (int n = 0; n < 4; ++n)
          acc[m][n] = __builtin_amdgcn_mfma_f32_16x16x32_f16(af[m], bf[n], acc[m][n], 0, 0, 0);
    }
    __syncthreads();
  }

  if (MODE == 0) {
    // epilogue: per-row sums of exp(-2*dist) over this tile's 128 cols
    #pragma unroll
    for (int m = 0; m < 4; ++m) {
      #pragma unroll
      for (int j = 0; j < 4; ++j) {
        int rl = wr * 64 + m * 16 + ((lane >> 4) << 2) + j;   // C/D: row=(lane>>4)*4+j
        float x2v = x2s[rl];
        float sm = 0.f;
        #pragma unroll
        for (int n = 0; n < 4; ++n) {
          int cl = wc * 64 + n * 16 + (lane & 15);            // C/D: col=lane&15
          float d2 = fmaxf(x2v + w2s[cl] - 2.0f * acc[m][n][j], 0.0f);
          sm += __expf(-2.0f * sqrtf(d2));
        }
        // reduce across the 16 lanes (lane&15) sharing this row
        sm += __shfl_xor(sm, 1);
        sm += __shfl_xor(sm, 2);
        sm += __shfl_xor(sm, 4);
        sm += __shfl_xor(sm, 8);
        if ((lane & 15) == 0) rowpart[wc][rl] = sm;
      }
    }
    __syncthreads();
    if (tid < 128)
      partials[(size_t)(brow + tid) * NTILE + ct] = rowpart[0][tid] + rowpart[1][tid];
  } else {
    // epilogue: out = exp(-2*dist) * inv_rowsum
    #pragma unroll
    for (int m = 0; m < 4; ++m) {
      #pragma unroll
      for (int j = 0; j < 4; ++j) {
        int rl = wr * 64 + m * 16 + ((lane >> 4) << 2) + j;
        float x2v = x2s[rl];
        float inv = invs[rl];
        size_t rowbase = (size_t)(brow + rl) * N_COLS + bcol;
        #pragma unroll
        for (int n = 0; n < 4; ++n) {
          int cl = wc * 64 + n * 16 + (lane & 15);
          float d2 = fmaxf(x2v + w2s[cl] - 2.0f * acc[m][n][j], 0.0f);
          out[rowbase + cl] = __expf(-2.0f * sqrtf(d2)) * inv;
        }
      }
    }
  }
}

// ------------- reduce partials -> 1/rowsum, one wave per row -----------
__global__ __launch_bounds__(256) void reduce_inv(
    const float* __restrict__ partials, float* __restrict__ invg) {
  int row  = blockIdx.x * 4 + (threadIdx.x >> 6);
  int lane = threadIdx.x & 63;
  const float* p = partials + (size_t)row * NTILE;
  float s = p[lane] + p[lane + 64];
  #pragma unroll
  for (int off = 32; off > 0; off >>= 1) s += __shfl_down(s, off);
  if (lane == 0) invg[row] = 1.0f / s;
}

// =============== fallback path (ws too small): round-0 scheme ===============
template <bool WS>
__global__ __launch_bounds__(256, 2) void gemm_logit(
    const void* __restrict__ Aptr, const void* __restrict__ Bptr,
    const float* __restrict__ x2g, const float* __restrict__ w2g,
    float* __restrict__ out, int mbase) {
  __shared__ _Float16 As[128 * 64];
  __shared__ _Float16 Bs[128 * 64];
  __shared__ float x2s[128];
  __shared__ float w2s[128];

  int id  = blockIdx.x;            // grid = 16 row-tiles * 128 col-tiles = 2048
  int xcd = id & 7;
  int rt  = (id >> 3) & 15;
  int c2  = id >> 7;               // [0,16)
  int brow = mbase + rt * 128;
  int bcol = (xcd * 16 + c2) * 128;

  int tid = threadIdx.x, lane = tid & 63, wid = tid >> 6;
  int wr = wid >> 1, wc = wid & 1;

  vf4 acc[4][4] = {};

  const float* xf = (const float*)Aptr;
  const float* wf = (const float*)Bptr;
  {
    const float* src = (tid < 128) ? xf + (size_t)(brow + tid) * K_DIM
                                   : wf + (size_t)(bcol + tid - 128) * K_DIM;
    float s = 0.f;
    for (int i = 0; i < 64; ++i) {
      float4 v = ((const float4*)src)[i];
      s += v.x*v.x + v.y*v.y + v.z*v.z + v.w*v.w;
    }
    if (tid < 128) x2s[tid] = s; else w2s[tid - 128] = s;
  }

  for (int kk = 0; kk < K_DIM; kk += 64) {
    #pragma unroll
    for (int i = 0; i < 8; ++i) {
      int idx = i * 256 + tid;               // 2048 float4 per tile
      int r = idx >> 4, kq = idx & 15;
      float4 va = ((const float4*)(xf + (size_t)(brow + r) * K_DIM + kk))[kq];
      float4 vb = ((const float4*)(wf + (size_t)(bcol + r) * K_DIM + kk))[kq];
      half4v ha; ha[0]=(_Float16)va.x; ha[1]=(_Float16)va.y; ha[2]=(_Float16)va.z; ha[3]=(_Float16)va.w;
      half4v hb; hb[0]=(_Float16)vb.x; hb[1]=(_Float16)vb.y; hb[2]=(_Float16)vb.z; hb[3]=(_Float16)vb.w;
      *(half4v*)&As[r * 64 + kq * 4] = ha;
      *(half4v*)&Bs[r * 64 + kq * 4] = hb;
    }
    __syncthreads();
    #pragma unroll
    for (int ks = 0; ks < 2; ++ks) {
      half8 af[4], bf[4];
      #pragma unroll
      for (int m = 0; m < 4; ++m)
        af[m] = *(const half8*)&As[(wr*64 + m*16 + (lane & 15)) * 64 + ks*32 + (lane >> 4) * 8];
      #pragma unroll
      for (int n = 0; n < 4; ++n)
        bf[n] = *(const half8*)&Bs[(wc*64 + n*16 + (lane & 15)) * 64 + ks*32 + (lane >> 4) * 8];
      #pragma unroll
      for (int m = 0; m < 4; ++m)
        #pragma unroll
        for (int n = 0; n < 4; ++n)
          acc[m][n] = __builtin_amdgcn_mfma_f32_16x16x32_f16(af[m], bf[n], acc[m][n], 0, 0, 0);
    }
    __syncthreads();
  }

  #pragma unroll
  for (int m = 0; m < 4; ++m) {
    int rl = wr * 64 + m * 16 + ((lane >> 4) << 2);
    #pragma unroll
    for (int n = 0; n < 4; ++n) {
      int cl = wc * 64 + n * 16 + (lane & 15);
      int c  = bcol + cl;
      float w2v = w2s[cl];
      #pragma unroll
      for (int j = 0; j < 4; ++j) {
        int r = brow + rl + j;
        float x2v = x2s[rl + j];
        float d2 = fmaxf(x2v + w2v - 2.0f * acc[m][n][j], 0.0f);
        out[(size_t)r * N_COLS + c] = -2.0f * sqrtf(d2);
      }
    }
  }
}

__global__ __launch_bounds__(256) void softmax_norm(float* __restrict__ io, int mbase) {
  int row = mbase + blockIdx.x;
  float* p = io + (size_t)row * N_COLS;
  int tid = threadIdx.x;
  __shared__ float wsum[4];

  float4 v[16];
  float s = 0.f;
  #pragma unroll
  for (int i = 0; i < 16; ++i) {
    v[i] = ((const float4*)p)[i * 256 + tid];
    v[i].x = __expf(v[i].x); v[i].y = __expf(v[i].y);
    v[i].z = __expf(v[i].z); v[i].w = __expf(v[i].w);
    s += v[i].x + v[i].y + v[i].z + v[i].w;
  }
  #pragma unroll
  for (int off = 32; off > 0; off >>= 1) s += __shfl_down(s, off);
  if ((tid & 63) == 0) wsum[tid >> 6] = s;
  __syncthreads();
  float inv = 1.0f / (wsum[0] + wsum[1] + wsum[2] + wsum[3]);
  #pragma unroll
  for (int i = 0; i < 16; ++i) {
    float4 o = v[i];
    o.x *= inv; o.y *= inv; o.z *= inv; o.w *= inv;
    ((float4*)p)[i * 256 + tid] = o;
  }
}

extern "C" void kernel_launch(void* const* d_in, const int* in_sizes, int n_in,
                              void* d_out, int out_size, void* d_ws, size_t ws_size,
                              hipStream_t stream) {
  const float* x = (const float*)d_in[0];
  const float* w = (const float*)d_in[1];
  float* out = (float*)d_out;

  // ws layout: x2[8192] | w2[16384] | invsum[8192] | partials[8192*128] |
  //            xh fp16 [8192*256] | wh fp16 [16384*256]
  char* ws = (char*)d_ws;
  float* x2 = (float*)ws;
  float* w2 = x2 + M_ROWS;
  float* invsum = w2 + N_COLS;
  float* partials = invsum + M_ROWS;
  _Float16* xh = (_Float16*)(partials + (size_t)M_ROWS * NTILE);
  _Float16* wh = xh + (size_t)M_ROWS * K_DIM;
  const size_t need = ((size_t)(M_ROWS + N_COLS + M_ROWS) + (size_t)M_ROWS * NTILE) * 4
                    + (size_t)(M_ROWS + N_COLS) * K_DIM * 2;
  const bool useWS = (ws_size >= need);

  if (useWS) {
    prep_kernel<<<(M_ROWS + N_COLS) / 4, 256, 0, stream>>>(x, w, x2, w2, xh, wh);
    gemm_pass<0><<<(M_ROWS / 128) * (N_COLS / 128), 256, 0, stream>>>(
        xh, wh, x2, w2, nullptr, partials, nullptr);
    reduce_inv<<<M_ROWS / 4, 256, 0, stream>>>(partials, invsum);
    gemm_pass<1><<<(M_ROWS / 128) * (N_COLS / 128), 256, 0, stream>>>(
        xh, wh, x2, w2, invsum, nullptr, out);
  } else {
    for (int c = 0; c < NCHUNK; ++c) {
      int mbase = c * CHUNK;
      gemm_logit<false><<<(CHUNK / 128) * (N_COLS / 128), 256, 0, stream>>>(
          x, w, nullptr, nullptr, out, mbase);
      softmax_norm<<<CHUNK, 256, 0, stream>>>(out, mbase);
    }
  }
}